// Round 10
// baseline (220.903 us; speedup 1.0000x reference)
//
#include <hip/hip_runtime.h>
#include <stdint.h>

// ---------------------------------------------------------------------------
// UnifiedEnergyFunction: total/hopfield/consistency/regularization scalars.
//   hopfield = mean_b( -logsumexp_n( z[b,:] . M[n,:] ) )
//   consistency = mean_b ||z - z_next||^2
//   regularization = 0.01 * mean_b ||z||^2
// v10 = v9's barrier-free stream (M pre-packed L2->reg, zf resident, double
// accumulator drain) moved to 32x32x16 MFMA: half the MFMA instructions per
// FLOP (denser issue stream) and a 17% cheaper matrix-pipe cost (2495 vs
// 2176 TF ceiling). Drain exp2s are hand-interleaved: 8 before each MFMA
// half-loop (hides the af load latency) + 1 per kq step inside it.
// ---------------------------------------------------------------------------

typedef __attribute__((ext_vector_type(8))) short short8;
typedef __attribute__((ext_vector_type(16))) float f32x16;

#define N_PAT  65536
#define D_DIM  256
#define B_ROWS 4096
#define NSPLIT 16                 // M ranges (2 per XCD, 2MB each) — proven
#define NRANGE (N_PAT / NSPLIT)   // 4096 rows per range
#define GPR    (NRANGE / 32)      // 128 32-row fragment groups per range
#define GPERW  (GPR / 2)          // 64 groups per wave (nh parity split)
#define BBLK   128                // b rows per block (2 bh x 64)
#define SHIFT2 69.0f              // fixed shift in log2 domain (~48 nats)
#define LOG2E  1.44269504f
#define LN2    0.69314718f

// workspace layout (bytes)
#define WS_M_OFF   ((size_t)0)
#define WS_M_BYTES ((size_t)N_PAT * D_DIM * 2)      // 32 MB packed bf16 M
#define WS_Z_OFF   (WS_M_OFF + WS_M_BYTES)
#define WS_Z_BYTES ((size_t)B_ROWS * D_DIM * 2)     // 2 MB bf16 z*log2e
#define WS_LSE_OFF (WS_Z_OFF + WS_Z_BYTES)
#define WS_LSE_BYTES ((size_t)B_ROWS * NSPLIT * 2 * 4) // float S per (b, 32 parts)
#define WS_CSS_OFF (WS_LSE_OFF + WS_LSE_BYTES)
#define WS_ZSS_OFF (WS_CSS_OFF + (size_t)512 * 4)

__device__ __forceinline__ short f2bf(float f) {
  uint32_t u = __float_as_uint(f);
  uint32_t r = (u + 0x7fffu + ((u >> 16) & 1u)) >> 16;
  return (short)(r & 0xffffu);
}

__device__ __forceinline__ float fexp2(float x) {
  return __builtin_amdgcn_exp2f(x);   // v_exp_f32 (hardware base-2 exp)
}

__device__ __forceinline__ float waveRedAdd(float v) {
  #pragma unroll
  for (int o = 32; o > 0; o >>= 1) v += __shfl_down(v, o, 64);
  return v;
}

// ---------------------------------------------------------------- kernel A1
// Convert M f32 -> bf16 AND repack into 32x32x16 A-fragment streaming order:
//   Mp[s][kq][lane][e] = M[s*32 + (lane&31)][kq*16 + (lane>>5)*8 + e]
// (s = 32-row fragment group 0..2047, kq = K-quad 0..15, e = 0..7)
__global__ void convert_m_kernel(const float* __restrict__ src, short* __restrict__ dst) {
  const int s = blockIdx.x * 4 + (threadIdx.x >> 6);  // 0..2047 (grid 512)
  const int lane = threadIdx.x & 63;
  const int l31 = lane & 31, hi = lane >> 5;
  const float* sp = src + ((size_t)s * 32 + l31) * D_DIM + hi * 8;
  short* dp = dst + ((size_t)s * 16 * 64 + lane) * 8;
  #pragma unroll
  for (int kq = 0; kq < 16; ++kq) {
    const float4 x = *(const float4*)(sp + kq * 16);
    const float4 y = *(const float4*)(sp + kq * 16 + 4);
    short8 o;
    o[0] = f2bf(x.x); o[1] = f2bf(x.y); o[2] = f2bf(x.z); o[3] = f2bf(x.w);
    o[4] = f2bf(y.x); o[5] = f2bf(y.y); o[6] = f2bf(y.z); o[7] = f2bf(y.w);
    *(short8*)(dp + (size_t)kq * 64 * 8) = o;
  }
}

// ---------------------------------------------------------------- kernel A2
// z -> bf16 scaled by log2(e), plus partial sums of ||z-zn||^2 and ||z||^2
__global__ void prep_z_kernel(const float* __restrict__ z, const float* __restrict__ zn,
                              short* __restrict__ zbf, float* __restrict__ css,
                              float* __restrict__ zss) {
  int t = blockIdx.x * 256 + threadIdx.x;  // 512 blocks x 256 = exactly B*D/8
  const float* az = z + (size_t)t * 8;
  const float* an = zn + (size_t)t * 8;
  float4 z0 = *(const float4*)(az), z1 = *(const float4*)(az + 4);
  float4 n0 = *(const float4*)(an), n1 = *(const float4*)(an + 4);
  float zv[8] = {z0.x, z0.y, z0.z, z0.w, z1.x, z1.y, z1.z, z1.w};
  float nv[8] = {n0.x, n0.y, n0.z, n0.w, n1.x, n1.y, n1.z, n1.w};
  short8 o;
  float cs = 0.f, zs = 0.f;
  #pragma unroll
  for (int j = 0; j < 8; ++j) {
    o[j] = f2bf(zv[j] * LOG2E);   // GEMM output lands in log2 domain
    float d = zv[j] - nv[j];
    cs += d * d;
    zs += zv[j] * zv[j];
  }
  *(short8*)(zbf + (size_t)t * 8) = o;

  __shared__ float rc[4], rz[4];
  cs = waveRedAdd(cs);
  zs = waveRedAdd(zs);
  int w = threadIdx.x >> 6, lane = threadIdx.x & 63;
  if (lane == 0) { rc[w] = cs; rz[w] = zs; }
  __syncthreads();
  if (threadIdx.x == 0) {
    css[blockIdx.x] = rc[0] + rc[1] + rc[2] + rc[3];
    zss[blockIdx.x] = rz[0] + rz[1] + rz[2] + rz[3];
  }
}

// ---------------------------------------------------------------- kernel B
// Barrier-free flash-LSE, 32x32x16 MFMA, 2-deep accumulator pipeline.
// 512 blocks x 4 waves; wave = (bh, nh): 64 b-cols (zf[2][16] resident),
// every other 32-row group of the block's 4096-n range.
// Per group: {init CUR | 8 drains | 16 MFMA (+1 drain/kq) | 8 loads |
//             8 drains | 16 MFMA (+1 drain/kq) | 8 loads (next group)}.
__global__ __launch_bounds__(256, 2) void lse_kernel(const short* __restrict__ Mp,
                                                     const short* __restrict__ zbf,
                                                     float* __restrict__ lsep) {
  const int bid = blockIdx.x;             // 512 blocks
  const int xcd = bid & 7;
  const int g = bid >> 3;                 // 0..63
  const int bblk = g & 31;
  const int half = g >> 5;
  const int nsplit = xcd * 2 + half;      // 2 ranges live per XCD

  const int tid = threadIdx.x;
  const int w = tid >> 6;
  const int lane = tid & 63;
  const int l31 = lane & 31;
  const int hi = lane >> 5;
  const int bh = w & 1;                   // b-half (64 cols = 2 bt x 32)
  const int nh = w >> 1;                  // group parity

  // hoist z fragments: 2 b-tiles x 16 k-quads = 128 regs (AGPR-resident)
  // B-frag 32x32x16: lane holds z[col=l31][kq*16 + hi*8 .. +8]
  short8 zf[2][16];
  const int brow0 = bblk * BBLK + bh * 64;
  #pragma unroll
  for (int bt = 0; bt < 2; ++bt) {
    #pragma unroll
    for (int kq = 0; kq < 16; ++kq) {
      int row = brow0 + bt * 32 + l31;
      zf[bt][kq] = *(const short8*)(zbf + (size_t)row * D_DIM + kq * 16 + hi * 8);
    }
  }

  // fragment stream: s = nsplit*128 + nh + 2*j; byte(s,kq,lane)=s*16384+kq*1024+lane*16
  const char* pj = (const char*)Mp + (size_t)(nsplit * GPR + nh) * 16384 + lane * 16;

  float ssum[2] = {0.f, 0.f};
  f32x16 accA[2], accB[2];
  short8 af[8];

  // accB pre-drained state: -inf so the first (dummy) drain adds exp2(-inf)=0
  #pragma unroll
  for (int bt = 0; bt < 2; ++bt)
    #pragma unroll
    for (int q = 0; q < 16; ++q) accB[bt][q] = -INFINITY;

  // prologue: group 0 first half (kq 0..7) in flight
  #pragma unroll
  for (int kc = 0; kc < 8; ++kc) af[kc] = *(const short8*)(pj + kc * 1024);

  // group body: compute CUR (32 MFMA), drain PREV (32 exp2) interleaved
  auto body = [&](f32x16 (&CUR)[2], f32x16 (&PREV)[2]) {
    const char* ph = pj + 8192;           // second half (kq 8..15)
    const char* pn = pj + 32768;          // next group (s += 2)

    #pragma unroll
    for (int bt = 0; bt < 2; ++bt)
      #pragma unroll
      for (int q = 0; q < 16; ++q) CUR[bt][q] = -SHIFT2;

    // pre-drain 8 of PREV[0] — executes while af's loads are still in flight
    #pragma unroll
    for (int e = 0; e < 8; ++e) ssum[0] += fexp2(PREV[0][e]);

    #pragma unroll
    for (int kq = 0; kq < 8; ++kq) {
      __builtin_amdgcn_s_setprio(1);
      CUR[0] = __builtin_amdgcn_mfma_f32_32x32x16_bf16(af[kq], zf[0][kq], CUR[0], 0, 0, 0);
      CUR[1] = __builtin_amdgcn_mfma_f32_32x32x16_bf16(af[kq], zf[1][kq], CUR[1], 0, 0, 0);
      __builtin_amdgcn_s_setprio(0);
      ssum[0] += fexp2(PREV[0][8 + kq]);
    }

    // reload af with kq 8..15 (in-order issue after the MFMAs that read it)
    #pragma unroll
    for (int kc = 0; kc < 8; ++kc) af[kc] = *(const short8*)(ph + kc * 1024);

    #pragma unroll
    for (int e = 0; e < 8; ++e) ssum[1] += fexp2(PREV[1][e]);

    #pragma unroll
    for (int kq = 0; kq < 8; ++kq) {
      __builtin_amdgcn_s_setprio(1);
      CUR[0] = __builtin_amdgcn_mfma_f32_32x32x16_bf16(af[kq], zf[0][8 + kq], CUR[0], 0, 0, 0);
      CUR[1] = __builtin_amdgcn_mfma_f32_32x32x16_bf16(af[kq], zf[1][8 + kq], CUR[1], 0, 0, 0);
      __builtin_amdgcn_s_setprio(0);
      ssum[1] += fexp2(PREV[1][8 + kq]);
    }

    // issue next group's first half (tail overshoot lands inside d_ws: harmless)
    #pragma unroll
    for (int kc = 0; kc < 8; ++kc) af[kc] = *(const short8*)(pn + kc * 1024);

    pj = pn;
  };

  #pragma unroll 1
  for (int jp = 0; jp < GPERW / 2; ++jp) {
    body(accA, accB);   // even group: compute A, drain B
    body(accB, accA);   // odd group:  compute B, drain A
  }

  // final drain (accB computed last)
  #pragma unroll
  for (int e = 0; e < 16; ++e) ssum[0] += fexp2(accB[0][e]);
  #pragma unroll
  for (int e = 0; e < 16; ++e) ssum[1] += fexp2(accB[1][e]);

  // lanes l and l+32 hold disjoint row-subsets of the same b-col: combine
  #pragma unroll
  for (int bt = 0; bt < 2; ++bt) ssum[bt] += __shfl_xor(ssum[bt], 32, 64);
  if (hi == 0) {
    #pragma unroll
    for (int bt = 0; bt < 2; ++bt) {
      int b = brow0 + bt * 32 + l31;
      lsep[(size_t)b * (NSPLIT * 2) + nsplit * 2 + nh] = ssum[bt];
    }
  }
}

// ---------------------------------------------------------------- kernel C
__global__ void finalize_kernel(const float* __restrict__ lsep, const float* __restrict__ css,
                                const float* __restrict__ zss, float* __restrict__ out) {
  __shared__ float r1[16], r2[16], r3[16];
  int tid = threadIdx.x;  // 1024
  float sum_lse = 0.f;
  for (int r = tid; r < B_ROWS; r += 1024) {
    float S = 0.f;
    #pragma unroll
    for (int i = 0; i < NSPLIT * 2; ++i) S += lsep[(size_t)r * (NSPLIT * 2) + i];
    sum_lse += SHIFT2 * LN2 + logf(S);   // back to nats
  }
  float cs = 0.f, zs = 0.f;
  if (tid < 512) { cs = css[tid]; zs = zss[tid]; }

  sum_lse = waveRedAdd(sum_lse);
  cs = waveRedAdd(cs);
  zs = waveRedAdd(zs);
  int w = tid >> 6, lane = tid & 63;
  if (lane == 0) { r1[w] = sum_lse; r2[w] = cs; r3[w] = zs; }
  __syncthreads();
  if (tid == 0) {
    float sl = 0.f, sc = 0.f, sz = 0.f;
    #pragma unroll
    for (int i = 0; i < 16; ++i) { sl += r1[i]; sc += r2[i]; sz += r3[i]; }
    float hop = -sl / (float)B_ROWS;
    float cons = sc / (float)B_ROWS;
    float reg = 0.01f * sz / (float)B_ROWS;
    out[0] = hop + cons + reg;
    out[1] = hop;
    out[2] = cons;
    out[3] = reg;
  }
}

// ---------------------------------------------------------------------------
extern "C" void kernel_launch(void* const* d_in, const int* in_sizes, int n_in,
                              void* d_out, int out_size, void* d_ws, size_t ws_size,
                              hipStream_t stream) {
  (void)in_sizes; (void)n_in; (void)out_size; (void)ws_size;
  const float* z  = (const float*)d_in[0];
  const float* zn = (const float*)d_in[1];
  const float* M  = (const float*)d_in[2];
  char* ws = (char*)d_ws;
  short* Mp  = (short*)(ws + WS_M_OFF);
  short* zbf = (short*)(ws + WS_Z_OFF);
  float* lsep = (float*)(ws + WS_LSE_OFF);
  float* css = (float*)(ws + WS_CSS_OFF);
  float* zss = (float*)(ws + WS_ZSS_OFF);

  convert_m_kernel<<<512, 256, 0, stream>>>(M, Mp);
  prep_z_kernel<<<512, 256, 0, stream>>>(z, zn, zbf, css, zss);
  lse_kernel<<<512, 256, 0, stream>>>(Mp, zbf, lsep);
  finalize_kernel<<<1, 1024, 0, stream>>>(lsep, css, zss, (float*)d_out);
}

// Round 11
// 172.748 us; speedup vs baseline: 1.2788x; 1.2788x over previous
//
#include <hip/hip_runtime.h>
#include <stdint.h>

// ---------------------------------------------------------------------------
// UnifiedEnergyFunction: total/hopfield/consistency/regularization scalars.
//   hopfield = mean_b( -logsumexp_n( z[b,:] . M[n,:] ) )
//   consistency = mean_b ||z - z_next||^2
//   regularization = 0.01 * mean_b ||z||^2
// v11 = v9's barrier-free 16x16x32 stream, resized for 4 waves/SIMD occupancy:
// 32 b-cols/wave (zf 64 regs), af 16, acc 8 -> ~112 regs <= 128 budget
// (__launch_bounds__(256,4)). 1024 blocks (4/CU); block = 4 waves x 32 b,
// nh-parity n-split; all 4 waves share one A-frag stream (L1-friendly).
// v10's 32x32 double-acc REVERTED (69 MB spill, -80%).
// ---------------------------------------------------------------------------

typedef __attribute__((ext_vector_type(8))) short short8;
typedef __attribute__((ext_vector_type(4))) float f32x4;

#define N_PAT  65536
#define D_DIM  256
#define B_ROWS 4096
#define NSPLIT 16                 // M ranges (2 per XCD, 2MB each) — proven
#define NRANGE (N_PAT / NSPLIT)   // 4096 rows per range
#define SPR    (NRANGE / 16)      // 256 16-row fragment groups per range
#define SPERW  (SPR / 2)          // 128 groups per wave (nh parity split)
#define BBLK   128                // b rows per block (4 waves x 32)
#define SHIFT2 69.0f              // fixed shift in log2 domain (~48 nats)
#define LOG2E  1.44269504f
#define LN2    0.69314718f

// workspace layout (bytes)
#define WS_M_OFF   ((size_t)0)
#define WS_M_BYTES ((size_t)N_PAT * D_DIM * 2)      // 32 MB packed bf16 M
#define WS_Z_OFF   (WS_M_OFF + WS_M_BYTES)
#define WS_Z_BYTES ((size_t)B_ROWS * D_DIM * 2)     // 2 MB bf16 z*log2e
#define WS_LSE_OFF (WS_Z_OFF + WS_Z_BYTES)
#define WS_LSE_BYTES ((size_t)B_ROWS * NSPLIT * 2 * 4) // float S per (b, 32 parts)
#define WS_CSS_OFF (WS_LSE_OFF + WS_LSE_BYTES)
#define WS_ZSS_OFF (WS_CSS_OFF + (size_t)512 * 4)

__device__ __forceinline__ short f2bf(float f) {
  uint32_t u = __float_as_uint(f);
  uint32_t r = (u + 0x7fffu + ((u >> 16) & 1u)) >> 16;
  return (short)(r & 0xffffu);
}

__device__ __forceinline__ float fexp2(float x) {
  return __builtin_amdgcn_exp2f(x);   // v_exp_f32 (hardware base-2 exp)
}

__device__ __forceinline__ float waveRedAdd(float v) {
  #pragma unroll
  for (int o = 32; o > 0; o >>= 1) v += __shfl_down(v, o, 64);
  return v;
}

// ---------------------------------------------------------------- kernel A1
// Convert M f32 -> bf16 AND repack into 16x16x32 A-fragment streaming order:
//   Mp[s][kc][lane][e] = M[s*16 + (lane&15)][kc*32 + (lane>>4)*8 + e]
__global__ void convert_m_kernel(const float* __restrict__ src, short* __restrict__ dst) {
  const int s = blockIdx.x * 4 + (threadIdx.x >> 6);  // 0..4095 (grid 1024)
  const int lane = threadIdx.x & 63;
  const int l15 = lane & 15, grp = lane >> 4;
  const float* sp = src + ((size_t)s * 16 + l15) * D_DIM + grp * 8;
  short* dp = dst + ((size_t)s * 8 * 64 + lane) * 8;
  #pragma unroll
  for (int kc = 0; kc < 8; ++kc) {
    const float4 x = *(const float4*)(sp + kc * 32);
    const float4 y = *(const float4*)(sp + kc * 32 + 4);
    short8 o;
    o[0] = f2bf(x.x); o[1] = f2bf(x.y); o[2] = f2bf(x.z); o[3] = f2bf(x.w);
    o[4] = f2bf(y.x); o[5] = f2bf(y.y); o[6] = f2bf(y.z); o[7] = f2bf(y.w);
    *(short8*)(dp + (size_t)kc * 64 * 8) = o;
  }
}

// ---------------------------------------------------------------- kernel A2
// z -> bf16 scaled by log2(e), plus partial sums of ||z-zn||^2 and ||z||^2
__global__ void prep_z_kernel(const float* __restrict__ z, const float* __restrict__ zn,
                              short* __restrict__ zbf, float* __restrict__ css,
                              float* __restrict__ zss) {
  int t = blockIdx.x * 256 + threadIdx.x;  // 512 blocks x 256 = exactly B*D/8
  const float* az = z + (size_t)t * 8;
  const float* an = zn + (size_t)t * 8;
  float4 z0 = *(const float4*)(az), z1 = *(const float4*)(az + 4);
  float4 n0 = *(const float4*)(an), n1 = *(const float4*)(an + 4);
  float zv[8] = {z0.x, z0.y, z0.z, z0.w, z1.x, z1.y, z1.z, z1.w};
  float nv[8] = {n0.x, n0.y, n0.z, n0.w, n1.x, n1.y, n1.z, n1.w};
  short8 o;
  float cs = 0.f, zs = 0.f;
  #pragma unroll
  for (int j = 0; j < 8; ++j) {
    o[j] = f2bf(zv[j] * LOG2E);   // GEMM output lands in log2 domain
    float d = zv[j] - nv[j];
    cs += d * d;
    zs += zv[j] * zv[j];
  }
  *(short8*)(zbf + (size_t)t * 8) = o;

  __shared__ float rc[4], rz[4];
  cs = waveRedAdd(cs);
  zs = waveRedAdd(zs);
  int w = threadIdx.x >> 6, lane = threadIdx.x & 63;
  if (lane == 0) { rc[w] = cs; rz[w] = zs; }
  __syncthreads();
  if (threadIdx.x == 0) {
    css[blockIdx.x] = rc[0] + rc[1] + rc[2] + rc[3];
    zss[blockIdx.x] = rz[0] + rz[1] + rz[2] + rz[3];
  }
}

// ---------------------------------------------------------------- kernel B
// Barrier-free flash-LSE at 4 waves/SIMD. 1024 blocks x 4 waves.
// Block = (nsplit, bblk, nh); wave w owns b-cols [bblk*128 + w*32, +32).
// Per 16-row group: {init acc | 8 MFMA (kc 0-3) | load kc 4-7 | 8 MFMA |
// load next group kc 0-3 | 8 exp2 drain}. TLP (4 waves) hides all latency.
__global__ __launch_bounds__(256, 4) void lse_kernel(const short* __restrict__ Mp,
                                                     const short* __restrict__ zbf,
                                                     float* __restrict__ lsep) {
  const int bid = blockIdx.x;             // 1024 blocks
  const int xcd = bid & 7;
  const int g = bid >> 3;                 // 0..127
  const int half = g >> 6;
  const int nsplit = xcd * 2 + half;      // 2 ranges live per XCD
  const int rem = g & 63;
  const int bblk = rem & 31;
  const int nh = rem >> 5;                // group parity

  const int tid = threadIdx.x;
  const int w = tid >> 6;
  const int lane = tid & 63;
  const int l15 = lane & 15;
  const int grp = lane >> 4;

  // hoist z fragments: 2 b-subtiles x 8 k-chunks = 64 regs
  short8 zf[2][8];
  const int brow0 = bblk * BBLK + w * 32;
  #pragma unroll
  for (int bt = 0; bt < 2; ++bt) {
    #pragma unroll
    for (int kc = 0; kc < 8; ++kc) {
      int row = brow0 + bt * 16 + l15;
      zf[bt][kc] = *(const short8*)(zbf + (size_t)row * D_DIM + kc * 32 + grp * 8);
    }
  }

  // fragment stream: s = nsplit*256 + nh + 2*j; byte(s,kc,lane)=s*8192+kc*1024+lane*16
  const char* pj = (const char*)Mp + (size_t)(nsplit * SPR + nh) * 8192 + lane * 16;

  float ssum[2] = {0.f, 0.f};
  f32x4 acc[2];
  short8 af[4];

  // prologue: group 0 first half (kc 0..3) in flight
  #pragma unroll
  for (int kc = 0; kc < 4; ++kc) af[kc] = *(const short8*)(pj + kc * 1024);

  #pragma unroll 1
  for (int j = 0; j < SPERW; ++j) {
    const char* ph = pj + 4096;           // kc 4..7 of this group
    const char* pn = pj + 16384;          // next group (s += 2)

    #pragma unroll
    for (int bt = 0; bt < 2; ++bt)
      #pragma unroll
      for (int q = 0; q < 4; ++q) acc[bt][q] = -SHIFT2;

    __builtin_amdgcn_s_setprio(1);
    #pragma unroll
    for (int kc = 0; kc < 4; ++kc) {
      acc[0] = __builtin_amdgcn_mfma_f32_16x16x32_bf16(af[kc], zf[0][kc], acc[0], 0, 0, 0);
      acc[1] = __builtin_amdgcn_mfma_f32_16x16x32_bf16(af[kc], zf[1][kc], acc[1], 0, 0, 0);
    }
    __builtin_amdgcn_s_setprio(0);

    #pragma unroll
    for (int kc = 0; kc < 4; ++kc) af[kc] = *(const short8*)(ph + kc * 1024);

    __builtin_amdgcn_s_setprio(1);
    #pragma unroll
    for (int kc = 0; kc < 4; ++kc) {
      acc[0] = __builtin_amdgcn_mfma_f32_16x16x32_bf16(af[kc], zf[0][kc + 4], acc[0], 0, 0, 0);
      acc[1] = __builtin_amdgcn_mfma_f32_16x16x32_bf16(af[kc], zf[1][kc + 4], acc[1], 0, 0, 0);
    }
    __builtin_amdgcn_s_setprio(0);

    // prefetch next group's first half (tail overshoot lands inside d_ws)
    #pragma unroll
    for (int kc = 0; kc < 4; ++kc) af[kc] = *(const short8*)(pn + kc * 1024);

    // drain: acc = log2-logit - SHIFT2; other waves' MFMAs cover this
    #pragma unroll
    for (int bt = 0; bt < 2; ++bt)
      ssum[bt] += (fexp2(acc[bt][0]) + fexp2(acc[bt][1])) +
                  (fexp2(acc[bt][2]) + fexp2(acc[bt][3]));

    pj = pn;
  }

  // 4 lane-groups hold different n-rows of each fragment for the same b-col
  #pragma unroll
  for (int bt = 0; bt < 2; ++bt) {
    ssum[bt] += __shfl_xor(ssum[bt], 16, 64);
    ssum[bt] += __shfl_xor(ssum[bt], 32, 64);
  }
  if (grp == 0) {
    #pragma unroll
    for (int bt = 0; bt < 2; ++bt) {
      int b = brow0 + bt * 16 + l15;
      lsep[(size_t)b * (NSPLIT * 2) + nsplit * 2 + nh] = ssum[bt];
    }
  }
}

// ---------------------------------------------------------------- kernel C
__global__ void finalize_kernel(const float* __restrict__ lsep, const float* __restrict__ css,
                                const float* __restrict__ zss, float* __restrict__ out) {
  __shared__ float r1[16], r2[16], r3[16];
  int tid = threadIdx.x;  // 1024
  float sum_lse = 0.f;
  for (int r = tid; r < B_ROWS; r += 1024) {
    float S = 0.f;
    #pragma unroll
    for (int i = 0; i < NSPLIT * 2; ++i) S += lsep[(size_t)r * (NSPLIT * 2) + i];
    sum_lse += SHIFT2 * LN2 + logf(S);   // back to nats
  }
  float cs = 0.f, zs = 0.f;
  if (tid < 512) { cs = css[tid]; zs = zss[tid]; }

  sum_lse = waveRedAdd(sum_lse);
  cs = waveRedAdd(cs);
  zs = waveRedAdd(zs);
  int w = tid >> 6, lane = tid & 63;
  if (lane == 0) { r1[w] = sum_lse; r2[w] = cs; r3[w] = zs; }
  __syncthreads();
  if (tid == 0) {
    float sl = 0.f, sc = 0.f, sz = 0.f;
    #pragma unroll
    for (int i = 0; i < 16; ++i) { sl += r1[i]; sc += r2[i]; sz += r3[i]; }
    float hop = -sl / (float)B_ROWS;
    float cons = sc / (float)B_ROWS;
    float reg = 0.01f * sz / (float)B_ROWS;
    out[0] = hop + cons + reg;
    out[1] = hop;
    out[2] = cons;
    out[3] = reg;
  }
}

// ---------------------------------------------------------------------------
extern "C" void kernel_launch(void* const* d_in, const int* in_sizes, int n_in,
                              void* d_out, int out_size, void* d_ws, size_t ws_size,
                              hipStream_t stream) {
  (void)in_sizes; (void)n_in; (void)out_size; (void)ws_size;
  const float* z  = (const float*)d_in[0];
  const float* zn = (const float*)d_in[1];
  const float* M  = (const float*)d_in[2];
  char* ws = (char*)d_ws;
  short* Mp  = (short*)(ws + WS_M_OFF);
  short* zbf = (short*)(ws + WS_Z_OFF);
  float* lsep = (float*)(ws + WS_LSE_OFF);
  float* css = (float*)(ws + WS_CSS_OFF);
  float* zss = (float*)(ws + WS_ZSS_OFF);

  convert_m_kernel<<<1024, 256, 0, stream>>>(M, Mp);
  prep_z_kernel<<<512, 256, 0, stream>>>(z, zn, zbf, css, zss);
  lse_kernel<<<1024, 256, 0, stream>>>(Mp, zbf, lsep);
  finalize_kernel<<<1, 1024, 0, stream>>>(lsep, css, zss, (float*)d_out);
}